// Round 6
// baseline (842.774 us; speedup 1.0000x reference)
//
#include <hip/hip_runtime.h>
#include <hip/hip_fp16.h>

// Problem constants
#define ORDER   2048
#define IN_DIM  64
#define T_LEN   4096

// Chunked-scan: J chunks of length L, warmup W. Per-multiply shrinkage of
// this A is ~0.404; warmup error ||A^11|| * ||h|| ~ 7e-3 vector-norm ->
// ~1e-3 peak/component, tanh-compressed. W=12 VALIDATED ON HW in r5:
// absmax 0.00390625 (identical to W=32/W=16 -> fp16 floor, not warmup).
// Chunk 0 is exact regardless of W (bu_{-1}=1 injects h0=1 onto an exactly
// zero warm state). S = W + L - 1 = 27 sequential steps.
#define NCHUNK  256         // J
#define CLEN    16          // L = T_LEN / NCHUNK
#define WARM    12          // W (HW-validated r5)
#define S_STEPS (WARM + CLEN - 1)   // 27
#define NWG     256

// LAUNCH-ENVELOPE NOTE: hipLaunchCooperativeKernel SILENTLY rejects
// resource-heavy profiles (r3: absmax exactly 1.0 = kernel never ran).
// Proven-working: 256 wgs x 256 thr, 32 KB LDS, 128 VGPR (r5). This
// version: ~144-160 VGPR (oreg 16->32 regs), __launch_bounds__(256,2)
// (VGPR cap 256), and the launch return code is checked with a plain-
// launch fallback. The fallback cannot deadlock: capacity 2 wg/CU x 256
// CU = 512 >= 256 wgs, so all wgs are resident under any dispatch.
//
// OUTPUT-PATH NOTE (r5 post-mortem): 16-B stores at 64-B stride caused 4x
// WRITE_SIZE (239 MB vs 59 ideal) and ~5x FETCH (RMW allocate) — ~32
// MB/step of parasitic fabric traffic in the serial chain. 32-B granule
// flush (r2 pattern) measured EXACTLY-ideal WRITE_SIZE. Never store output
// in less than 32-B aligned granules.

typedef unsigned long long ull;
using half8v  = __attribute__((ext_vector_type(8))) _Float16;
using half4v  = __attribute__((ext_vector_type(4))) _Float16;
using float4v = __attribute__((ext_vector_type(4))) float;

#define AGLD(p) __hip_atomic_load((p), __ATOMIC_RELAXED, __HIP_MEMORY_SCOPE_AGENT)
#define MFMA16(av, bv, acc) \
    acc = __builtin_amdgcn_mfma_f32_16x16x32_f16((av), (bv), (acc), 0, 0, 0)

__global__ __launch_bounds__(256) void zero_kernel(float* __restrict__ p, int n) {
    int idx = blockIdx.x * 256 + threadIdx.x;
    if (idx < n) p[idx] = 0.0f;
}

// bu[t][i] = sum_d B[i][d] * u[d][t], fp32, layout [T_LEN][ORDER]. (r6-verified)
__global__ __launch_bounds__(256) void bu_kernel(const float* __restrict__ u,
                                                 const float* __restrict__ Bw,
                                                 float* __restrict__ bu) {
    __shared__ float lds_u[IN_DIM * 64];   // [d][tau_local]
    const int t0 = blockIdx.x * 64;
    const int i0 = blockIdx.y * 256;
    const int tid = threadIdx.x;
    for (int idx = tid; idx < IN_DIM * 64; idx += 256) {
        int d = idx >> 6, tt = idx & 63;
        lds_u[idx] = u[d * T_LEN + t0 + tt];
    }
    __syncthreads();
    const int w = __builtin_amdgcn_readfirstlane(tid >> 6);
    const int l = tid & 63;
    const int ib = i0 + w * 64;           // wave-uniform -> scalar B loads
    float acc[64];
#pragma unroll
    for (int s = 0; s < 64; ++s) acc[s] = 0.0f;
    for (int d = 0; d < IN_DIM; d += 4) {
        float u0 = lds_u[(d + 0) * 64 + l];
        float u1 = lds_u[(d + 1) * 64 + l];
        float u2 = lds_u[(d + 2) * 64 + l];
        float u3 = lds_u[(d + 3) * 64 + l];
#pragma unroll
        for (int s = 0; s < 64; ++s) {
            const float* br = Bw + (size_t)(ib + s) * IN_DIM + d;
            acc[s] += br[0] * u0 + br[1] * u1 + br[2] * u2 + br[3] * u3;
        }
    }
    float* dstp = bu + (size_t)(t0 + l) * ORDER + ib;
#pragma unroll
    for (int q = 0; q < 16; ++q) {
        float4v v = {acc[q * 4 + 0], acc[q * 4 + 1], acc[q * 4 + 2], acc[q * 4 + 3]};
        ((float4v*)dstp)[q] = v;
    }
}

// Pack A (fp32 row-major) into fp16 MFMA A-fragment order (r6-verified):
// ((half8v*)Ap)[R*4096 + c*64 + l] = A[R*16 + (l&15)][c*32 + (l>>4)*8 .. +8].
__global__ __launch_bounds__(256) void pack_kernel(const float* __restrict__ A,
                                                   _Float16* __restrict__ Ap) {
    int tid = blockIdx.x * 256 + threadIdx.x;   // 0 .. 128*64*64-1
    int l = tid & 63;
    int c = (tid >> 6) & 63;
    int R = tid >> 12;
    int row = R * 16 + (l & 15);
    int col = c * 32 + (l >> 4) * 8;
    const float4v* src = (const float4v*)(A + (size_t)row * ORDER + col);
    float4v f0 = src[0], f1 = src[1];
    half8v h;
    h[0] = (_Float16)f0[0]; h[1] = (_Float16)f0[1];
    h[2] = (_Float16)f0[2]; h[3] = (_Float16)f0[3];
    h[4] = (_Float16)f1[0]; h[5] = (_Float16)f1[1];
    h[6] = (_Float16)f1[2]; h[7] = (_Float16)f1[3];
    ((half8v*)Ap)[tid] = h;
}

// Flattened per-domain slot barrier (r2-verified). Domain = the 32 wgs
// sharing panel-pair p (they alone touch H panels 2p,2p+1). Arrival:
// tid==0 EXCHANGES the wg's monotone step count into its own 32-B-padded
// slot. Release: every wg's wave-0 lanes 0..31 poll the 32 slots, break on
// __all(slot >= want). Monotone -> no reset. Ordering: entry __syncthreads
// drains vmcnt, so all H exchanges of this wg are at the MALL before its
// slot is bumped (r6 discipline).
static __device__ __forceinline__ void domain_barrier(
        ull* __restrict__ slots, int rg, unsigned want) {
    __syncthreads();
    const int tid = threadIdx.x;
    if (tid == 0)
        (void)__hip_atomic_exchange(slots + (size_t)rg * 4, (ull)want,
                                    __ATOMIC_RELAXED, __HIP_MEMORY_SCOPE_AGENT);
    if (tid < 64) {          // wave 0: lanes 0..31 watch one slot each
        for (;;) {
            ull v = (tid < 32)
                ? AGLD(slots + (size_t)tid * 4)
                : ~0ull;
            if (__all(v >= (ull)want)) break;
            __builtin_amdgcn_s_sleep(1);
        }
    }
    __atomic_signal_fence(__ATOMIC_ACQUIRE);
    __syncthreads();
}

// One scan step. Each wave owns 32 columns: col n of panel 2p (j0) and col n
// of panel 2p+1 (j0+16). K=2048 is processed in 4 rounds of 16 K-chunks;
// each round stages BOTH panels' 16-chunk slab (16 KB + 16 KB = 32 KB LDS),
// so every A-fragment load feeds 2 MFMAs. Depth-1 prefetch: one pf[16]
// array holds round r+1 while round r computes (launch-envelope safe).
// SEG >= 0: record tanh outputs into static register slots (2 panels,
// octave granularity: oreg[pan][row][SEG>>1] halfword SEG&1, SEG 0..7).
template<int SEG>
static __device__ __forceinline__ void do_step(
        int k, bool last,
        const half8v* __restrict__ apb, const float* __restrict__ bu,
        _Float16* __restrict__ Ha, _Float16* __restrict__ Hb,
        ull* __restrict__ slots, ull* __restrict__ lds_h,
        int tid, int l, int rg, int p, int j0, int mrow, int granH,
        unsigned (&oreg)[2][4][4]) {
    const ull* __restrict__ srcb = (const ull*)((k & 1) ? Hb : Ha);
    ull* __restrict__ dstb       = (ull*)((k & 1) ? Ha : Hb);
    const ull* __restrict__ s0 = srcb + (size_t)(2 * p) * 8192;
    const ull* __restrict__ s1 = srcb + (size_t)(2 * p + 1) * 8192;
    ull* __restrict__ d0 = dstb + (size_t)(2 * p) * 8192;
    ull* __restrict__ d1 = dstb + (size_t)(2 * p + 1) * 8192;

    float4v acc00 = {0.f,0.f,0.f,0.f}, acc01 = {0.f,0.f,0.f,0.f};
    float4v acc10 = {0.f,0.f,0.f,0.f}, acc11 = {0.f,0.f,0.f,0.f};

    // Round 0: load -> regs -> LDS (transient); then prefetch round 1 into
    // pf. LDS layout per round: panel0 slab at ull [0,2048), panel1 at
    // [2048,4096); panel ull range for round rr is [rr*2048,(rr+1)*2048).
    ull pf[16];
    {
        ull t0r[16];
#pragma unroll
        for (int q = 0; q < 8; ++q) t0r[q]     = AGLD(s0 + q * 256 + tid);
#pragma unroll
        for (int q = 0; q < 8; ++q) t0r[8 + q] = AGLD(s1 + q * 256 + tid);
#pragma unroll
        for (int q = 0; q < 16; ++q) lds_h[q * 256 + tid] = t0r[q];
    }
#pragma unroll
    for (int q = 0; q < 8; ++q) pf[q]     = AGLD(s0 + 2048 + q * 256 + tid);
#pragma unroll
    for (int q = 0; q < 8; ++q) pf[8 + q] = AGLD(s1 + 2048 + q * 256 + tid);
    __syncthreads();

    // One round: 16 K-chunks, A-fragment reused for both panels (32 MFMAs).
#define COMPUTE_ROUND(rr)                                                    \
    {                                                                        \
        const half8v* __restrict__ lb0 = ((const half8v*)lds_h) + l;         \
        const half8v* __restrict__ lb1 = lb0 + 1024;                         \
        const half8v* __restrict__ ap  = apb + (rr) * 16 * 64;               \
        _Pragma("unroll")                                                    \
        for (int cc = 0; cc < 16; ++cc) {                                    \
            half8v av = ap[cc * 64];     /* global 16-B coalesced, L2 hit */ \
            half8v b0 = lb0[cc * 64];    /* ds_read_b128, conflict-free   */ \
            half8v b1 = lb1[cc * 64];                                        \
            if (cc & 1) { MFMA16(av, b0, acc01); MFMA16(av, b1, acc11); }    \
            else        { MFMA16(av, b0, acc00); MFMA16(av, b1, acc10); }    \
        }                                                                    \
    }

    COMPUTE_ROUND(0);
    __syncthreads();                     // LDS consumed
#pragma unroll
    for (int q = 0; q < 16; ++q) lds_h[q * 256 + tid] = pf[q];   // round 1
#pragma unroll
    for (int q = 0; q < 8; ++q) pf[q]     = AGLD(s0 + 4096 + q * 256 + tid);
#pragma unroll
    for (int q = 0; q < 8; ++q) pf[8 + q] = AGLD(s1 + 4096 + q * 256 + tid);
    __syncthreads();
    COMPUTE_ROUND(1);
    __syncthreads();
#pragma unroll
    for (int q = 0; q < 16; ++q) lds_h[q * 256 + tid] = pf[q];   // round 2
#pragma unroll
    for (int q = 0; q < 8; ++q) pf[q]     = AGLD(s0 + 6144 + q * 256 + tid);
#pragma unroll
    for (int q = 0; q < 8; ++q) pf[8 + q] = AGLD(s1 + 6144 + q * 256 + tid);
    __syncthreads();
    COMPUTE_ROUND(2);
    __syncthreads();
#pragma unroll
    for (int q = 0; q < 16; ++q) lds_h[q * 256 + tid] = pf[q];   // round 3
    __syncthreads();
    COMPUTE_ROUND(3);
#undef COMPUTE_ROUND
    // No trailing sync: next LDS write happens after the barrier's entry
    // __syncthreads (or never, on the last step).

    float4v hs0 = acc00 + acc01;
    float4v hs1 = acc10 + acc11;

    // Epilogue: h = A*h + bu_t per panel (C-layout: col = lane&15, row =
    // quad*4+r). Panel1's t is always >= 244 (chunk >= 16) -> unconditional.
    const int t0 = j0 * CLEN - WARM + k;
    float4v bv0;
    if (t0 >= 0) {
        bv0 = *(const float4v*)(bu + (size_t)t0 * ORDER + mrow);  // plain, L2
    } else {
        float v = (t0 == -1) ? 1.0f : 0.0f;  // bu_{-1}=1 injects h0=1 exactly
        bv0 = {v, v, v, v};
    }
    float4v bv1 = *(const float4v*)(bu + (size_t)(t0 + 256) * ORDER + mrow);
    float4v h0 = hs0 + bv0;
    float4v h1 = hs1 + bv1;

    // Next state: atomic EXCHANGE (RMW at the MALL -> cross-XCD coherent).
    union { half4v hh; ull u; } c0, c1;
    c0.hh[0] = (_Float16)h0[0]; c0.hh[1] = (_Float16)h0[1];
    c0.hh[2] = (_Float16)h0[2]; c0.hh[3] = (_Float16)h0[3];
    c1.hh[0] = (_Float16)h1[0]; c1.hh[1] = (_Float16)h1[1];
    c1.hh[2] = (_Float16)h1[2]; c1.hh[3] = (_Float16)h1[3];
    (void)__hip_atomic_exchange(d0 + granH, c0.u, __ATOMIC_RELAXED,
                                __HIP_MEMORY_SCOPE_AGENT);
    (void)__hip_atomic_exchange(d1 + granH, c1.u, __ATOMIC_RELAXED,
                                __HIP_MEMORY_SCOPE_AGENT);

    // Record tanh outputs into registers (static slot SEG; flushed per octave).
    if (SEG >= 0) {
#pragma unroll
        for (int r = 0; r < 4; ++r) {
            float x0 = h0[r];
            float e0 = __expf(-2.0f * fabsf(x0));
            float o0 = copysignf((1.0f - e0) / (1.0f + e0), x0);
            unsigned u0 = (unsigned)__half_as_ushort(__float2half_rn(o0));
            float x1 = h1[r];
            float e1 = __expf(-2.0f * fabsf(x1));
            float o1 = copysignf((1.0f - e1) / (1.0f + e1), x1);
            unsigned u1 = (unsigned)__half_as_ushort(__float2half_rn(o1));
            if (SEG & 1) {
                oreg[0][r][SEG >> 1] = (oreg[0][r][SEG >> 1] & 0xFFFFu) | (u0 << 16);
                oreg[1][r][SEG >> 1] = (oreg[1][r][SEG >> 1] & 0xFFFFu) | (u1 << 16);
            } else {
                oreg[0][r][SEG >> 1] = u0;
                oreg[1][r][SEG >> 1] = u1;
            }
        }
    }

    if (!last) domain_barrier(slots, rg, (unsigned)(k + 1));
}

// Persistent step kernel. Tiling: 128 row-blocks (16 rows) x 8 panel-pairs
// (32 chunks); wg = 4 waves = 4 consecutive row-blocks sharing the LDS-
// staged panel-pair slab (4 x 32 KB K-rounds). H: 8-B agent-scope atomic
// exchange stores / agent-scope staged loads. Outputs: fp16 pairs in
// registers, flushed every 8 steps as 32-B sectors (r2-proven-clean
// granularity; see OUTPUT-PATH NOTE).
__global__ __launch_bounds__(256, 2) void step_kernel(const _Float16* __restrict__ Ap,
                                                      const float* __restrict__ bu,
                                                      _Float16* __restrict__ Ha,
                                                      _Float16* __restrict__ Hb,
                                                      float* __restrict__ out,
                                                      ull* __restrict__ bar) {
    const int w    = blockIdx.x;         // 0..255
    const int xcd  = w & 7;              // MI355X blockIdx%8 -> XCD (perf only)
    const int idx  = w >> 3;             // 0..31
    const int rg   = xcd * 4 + (idx & 3);// 64-row group: 256-row slab per XCD
    const int p    = idx >> 2;           // 0..7: panel-pair (32 chunks)
    const int tid  = threadIdx.x;
    const int wave = tid >> 6;           // 0..3 -> row-block within group
    const int l    = tid & 63;
    const int n    = l & 15;
    const int quad = l >> 4;
    const int R    = rg * 4 + wave;      // global 16-row block, 0..127
    const int i0   = R * 16;
    const int j0   = p * 32 + n;         // this lane's chunk id, panel 2p
    const int mrow = i0 + quad * 4;

    __shared__ ull lds_h[4096];          // 32 KB (exact proven LDS profile)

    // Barrier state for domain p: 32 slots x 32 B.
    ull* slots = bar + (size_t)p * 128;

    // A fragments for this wave (coalesced 16-B loads, L2-resident).
    const half8v* __restrict__ apb = ((const half8v*)Ap) + (size_t)R * 4096 + l;

    // H-store granule within a panel (B-fragment order, r6-verified).
    const int granH = (((mrow >> 5) * 64) + (((mrow >> 3) & 3) * 16) + n) * 2
                    + ((mrow >> 2) & 1);

    unsigned oreg[2][4][4];              // 2 panels x 4 rows x 8 segs (fp16x2)

    // Phase A: warmup steps k = 0..WARM-2 (no output emitted).
    for (int k = 0; k < WARM - 1; ++k)
        do_step<-1>(k, false, apb, bu, Ha, Hb, slots, lds_h,
                    tid, l, rg, p, j0, mrow, granH, oreg);

    // Phase B: 2 octaves x 8 steps, k = WARM-1 .. S_STEPS-1; flush/octave.
    for (int g = 0; g < 2; ++g) {
        const int k0 = WARM - 1 + g * 8;
        const bool lg = (g == 1);
        do_step<0>(k0 + 0, false, apb, bu, Ha, Hb, slots, lds_h, tid, l, rg, p, j0, mrow, granH, oreg);
        do_step<1>(k0 + 1, false, apb, bu, Ha, Hb, slots, lds_h, tid, l, rg, p, j0, mrow, granH, oreg);
        do_step<2>(k0 + 2, false, apb, bu, Ha, Hb, slots, lds_h, tid, l, rg, p, j0, mrow, granH, oreg);
        do_step<3>(k0 + 3, false, apb, bu, Ha, Hb, slots, lds_h, tid, l, rg, p, j0, mrow, granH, oreg);
        do_step<4>(k0 + 4, false, apb, bu, Ha, Hb, slots, lds_h, tid, l, rg, p, j0, mrow, granH, oreg);
        do_step<5>(k0 + 5, false, apb, bu, Ha, Hb, slots, lds_h, tid, l, rg, p, j0, mrow, granH, oreg);
        do_step<6>(k0 + 6, false, apb, bu, Ha, Hb, slots, lds_h, tid, l, rg, p, j0, mrow, granH, oreg);
        do_step<7>(k0 + 7, lg,    apb, bu, Ha, Hb, slots, lds_h, tid, l, rg, p, j0, mrow, granH, oreg);

        // Flush octave g for both panels: rows mrow..mrow+3,
        // cols jj*16 + g*8 .. +8 (32-B contiguous per lane, 64-B stride
        // across n-lanes -> 2 lanes fill each 128-B line; r2-proven clean).
#pragma unroll
        for (int pan = 0; pan < 2; ++pan) {
            const int jj = j0 + pan * 16;
            float* __restrict__ ob = out + (size_t)mrow * T_LEN + jj * 16 + g * 8;
#pragma unroll
            for (int r = 0; r < 4; ++r) {
                float4v f0, f1;
#pragma unroll
                for (int q = 0; q < 2; ++q) {
                    unsigned v0 = oreg[pan][r][q * 2 + 0];
                    unsigned v1 = oreg[pan][r][q * 2 + 1];
                    float a0 = __half2float(__ushort_as_half((ushort)(v0 & 0xFFFFu)));
                    float a1 = __half2float(__ushort_as_half((ushort)(v0 >> 16)));
                    float a2 = __half2float(__ushort_as_half((ushort)(v1 & 0xFFFFu)));
                    float a3 = __half2float(__ushort_as_half((ushort)(v1 >> 16)));
                    if (q == 0) f0 = {a0, a1, a2, a3};
                    else        f1 = {a0, a1, a2, a3};
                }
                *(float4v*)(ob + (size_t)r * T_LEN)     = f0;
                *(float4v*)(ob + (size_t)r * T_LEN + 4) = f1;
            }
        }
    }
}

extern "C" void kernel_launch(void* const* d_in, const int* in_sizes, int n_in,
                              void* d_out, int out_size, void* d_ws, size_t ws_size,
                              hipStream_t stream) {
    const float* u  = (const float*)d_in[0];   // [IN_DIM][T_LEN]
    const float* A  = (const float*)d_in[1];   // [ORDER][ORDER]
    const float* Bw = (const float*)d_in[2];   // [ORDER][IN_DIM]
    float* out = (float*)d_out;                // [ORDER][T_LEN]

    char* ws = (char*)d_ws;
    float*     bu  = (float*)ws;                                 // 33,554,432 B
    _Float16*  Ap  = (_Float16*)(ws + 33554432);                 //  8,388,608 B
    _Float16*  Ha  = (_Float16*)(ws + 41943040);                 //  1,048,576 B
    _Float16*  Hb  = (_Float16*)(ws + 42991616);                 //  1,048,576 B
    ull*       bar = (ull*)(ws + 44040192);                      //      8,192 B

    // H_0 = zeros in Ha; barrier slots = 0 (ws poisoned 0xAA per call).
    zero_kernel<<<dim3(1024), 256, 0, stream>>>((float*)Ha, NCHUNK * ORDER / 2);
    zero_kernel<<<dim3(8), 256, 0, stream>>>((float*)bar, 2048);
    bu_kernel<<<dim3(64, 8), 256, 0, stream>>>(u, Bw, bu);
    pack_kernel<<<dim3(2048), 256, 0, stream>>>(A, Ap);

    void* args[] = {(void*)&Ap, (void*)&bu, (void*)&Ha, (void*)&Hb,
                    (void*)&out, (void*)&bar};
    hipError_t ce = hipLaunchCooperativeKernel((void*)step_kernel, dim3(NWG),
                                               dim3(256), args, 0, stream);
    if (ce != hipSuccess) {
        // Silent-rejection insurance: at 32 KB LDS / <=256 VGPR the capacity
        // is 2 wg/CU x 256 CU = 512 >= 256 wgs, so all wgs co-reside under a
        // plain launch and the slot barrier remains deadlock-free.
        (void)hipGetLastError();
        step_kernel<<<dim3(NWG), dim3(256), 0, stream>>>(Ap, bu, Ha, Hb, out,
                                                         (ull*)bar);
    }
}

// Round 7
// 604.104 us; speedup vs baseline: 1.3951x; 1.3951x over previous
//
#include <hip/hip_runtime.h>
#include <hip/hip_fp16.h>

// Problem constants
#define ORDER   2048
#define IN_DIM  64
#define T_LEN   4096

// Chunked-scan: J chunks of length L, warmup W. Per-multiply shrinkage of
// this A is ~0.404; W=12 HW-VALIDATED (r5, r6: absmax 0.00390625, same as
// W=16/W=32 -> fp16 rounding floor, not warmup error). Chunk 0 is exact
// regardless of W (bu_{-1}=1 injects h0=1 onto an exactly-zero warm state).
// S = W + L - 1 = 43 sequential steps.
//
// STRUCTURE NOTE (r5/r6 post-mortem): this is the r2-proven structure
// (NCHUNK=128, one 16-chunk panel per wg, 64 KB staged/wg/step, 2 K-halves,
// 10.7 us/step). The r5/r6 experiment (NCHUNK=256, 2 panels/wg, 128 KB
// staged/wg/step) ran at ~25 us/step — the doubled 8-B agent-scope staging
// traffic (32 MB/step device-wide, re-fetched past L2 every step because
// the atomic-exchange writes invalidate) more than erased the step-count
// win. Staged volume per wg per step is part of the proven profile.
#define NCHUNK  128         // J
#define CLEN    32          // L = T_LEN / NCHUNK
#define WARM    12          // W (HW-validated r5/r6)
#define S_STEPS (WARM + CLEN - 1)   // 43
#define NWG     256

// LAUNCH-ENVELOPE NOTE: hipLaunchCooperativeKernel SILENTLY rejects
// resource-heavy profiles (r3: absmax exactly 1.0 = kernel never ran).
// Proven-working: 256 wgs x 256 thr, 32 KB LDS, 100 VGPR (r2 = this exact
// kernel). Launch return code is checked with a plain-launch fallback; at
// 100 VGPR / 32 KB LDS, >=4 wg/CU fit, so all 256 wgs co-reside on 256 CUs
// under a plain launch and the slot barrier cannot deadlock.

typedef unsigned long long ull;
using half8v  = __attribute__((ext_vector_type(8))) _Float16;
using half4v  = __attribute__((ext_vector_type(4))) _Float16;
using float4v = __attribute__((ext_vector_type(4))) float;

#define AGLD(p) __hip_atomic_load((p), __ATOMIC_RELAXED, __HIP_MEMORY_SCOPE_AGENT)

__global__ __launch_bounds__(256) void zero_kernel(float* __restrict__ p, int n) {
    int idx = blockIdx.x * 256 + threadIdx.x;
    if (idx < n) p[idx] = 0.0f;
}

// bu[t][i] = sum_d B[i][d] * u[d][t], fp32, layout [T_LEN][ORDER]. (r6-verified)
__global__ __launch_bounds__(256) void bu_kernel(const float* __restrict__ u,
                                                 const float* __restrict__ Bw,
                                                 float* __restrict__ bu) {
    __shared__ float lds_u[IN_DIM * 64];   // [d][tau_local]
    const int t0 = blockIdx.x * 64;
    const int i0 = blockIdx.y * 256;
    const int tid = threadIdx.x;
    for (int idx = tid; idx < IN_DIM * 64; idx += 256) {
        int d = idx >> 6, tt = idx & 63;
        lds_u[idx] = u[d * T_LEN + t0 + tt];
    }
    __syncthreads();
    const int w = __builtin_amdgcn_readfirstlane(tid >> 6);
    const int l = tid & 63;
    const int ib = i0 + w * 64;           // wave-uniform -> scalar B loads
    float acc[64];
#pragma unroll
    for (int s = 0; s < 64; ++s) acc[s] = 0.0f;
    for (int d = 0; d < IN_DIM; d += 4) {
        float u0 = lds_u[(d + 0) * 64 + l];
        float u1 = lds_u[(d + 1) * 64 + l];
        float u2 = lds_u[(d + 2) * 64 + l];
        float u3 = lds_u[(d + 3) * 64 + l];
#pragma unroll
        for (int s = 0; s < 64; ++s) {
            const float* br = Bw + (size_t)(ib + s) * IN_DIM + d;
            acc[s] += br[0] * u0 + br[1] * u1 + br[2] * u2 + br[3] * u3;
        }
    }
    float* dstp = bu + (size_t)(t0 + l) * ORDER + ib;
#pragma unroll
    for (int q = 0; q < 16; ++q) {
        float4v v = {acc[q * 4 + 0], acc[q * 4 + 1], acc[q * 4 + 2], acc[q * 4 + 3]};
        ((float4v*)dstp)[q] = v;
    }
}

// Pack A (fp32 row-major) into fp16 MFMA A-fragment order (r6-verified):
// ((half8v*)Ap)[R*4096 + c*64 + l] = A[R*16 + (l&15)][c*32 + (l>>4)*8 .. +8].
__global__ __launch_bounds__(256) void pack_kernel(const float* __restrict__ A,
                                                   _Float16* __restrict__ Ap) {
    int tid = blockIdx.x * 256 + threadIdx.x;   // 0 .. 128*64*64-1
    int l = tid & 63;
    int c = (tid >> 6) & 63;
    int R = tid >> 12;
    int row = R * 16 + (l & 15);
    int col = c * 32 + (l >> 4) * 8;
    const float4v* src = (const float4v*)(A + (size_t)row * ORDER + col);
    float4v f0 = src[0], f1 = src[1];
    half8v h;
    h[0] = (_Float16)f0[0]; h[1] = (_Float16)f0[1];
    h[2] = (_Float16)f0[2]; h[3] = (_Float16)f0[3];
    h[4] = (_Float16)f1[0]; h[5] = (_Float16)f1[1];
    h[6] = (_Float16)f1[2]; h[7] = (_Float16)f1[3];
    ((half8v*)Ap)[tid] = h;
}

// Flattened per-domain slot barrier (r2-verified). Domain = the 32 wgs
// sharing jg (they alone touch H panel jg). Arrival: tid==0 EXCHANGES the
// wg's monotone step count into its own 32-B-padded slot. Release: every
// wg's wave-0 lanes 0..31 poll the 32 slots, break on __all(slot >= want).
// Monotone -> no reset. Ordering: entry __syncthreads drains vmcnt, so all
// H exchanges of this wg are at the MALL before its slot is bumped.
static __device__ __forceinline__ void domain_barrier(
        ull* __restrict__ slots, int rg, unsigned want) {
    __syncthreads();
    const int tid = threadIdx.x;
    if (tid == 0)
        (void)__hip_atomic_exchange(slots + (size_t)rg * 4, (ull)want,
                                    __ATOMIC_RELAXED, __HIP_MEMORY_SCOPE_AGENT);
    if (tid < 64) {          // wave 0: lanes 0..31 watch one slot each
        for (;;) {
            ull v = (tid < 32)
                ? AGLD(slots + (size_t)tid * 4)
                : ~0ull;
            if (__all(v >= (ull)want)) break;
            __builtin_amdgcn_s_sleep(1);
        }
    }
    __atomic_signal_fence(__ATOMIC_ACQUIRE);
    __syncthreads();
}

// One scan step (r2-verified body, 10.7 us/step measured). SEG >= 0: also
// record tanh output into the statically-indexed fp16-pair register buffer
// oreg[4][4]. Half-1's 16 agent loads are issued into registers right after
// half-0's staging issues, hiding the second MALL round-trip under half-0's
// MFMAs.
template<int SEG>
static __device__ __forceinline__ void do_step(
        int k, bool last,
        const half8v* __restrict__ apb, const float* __restrict__ bu,
        _Float16* __restrict__ Ha, _Float16* __restrict__ Hb,
        ull* __restrict__ slots, ull* __restrict__ lds_h,
        int tid, int l, int rg, int jg, int j, int mrow, int granH,
        unsigned (&oreg)[4][4]) {
    const ull* __restrict__ src = ((const ull*)((k & 1) ? Hb : Ha)) + jg * 8192;
    ull* __restrict__ dst       = ((ull*)((k & 1) ? Ha : Hb)) + jg * 8192;

    float4v acc0 = {0.f, 0.f, 0.f, 0.f};
    float4v acc1 = {0.f, 0.f, 0.f, 0.f};

    // Stage half 0 (K-chunks 0..31) directly into LDS; issue half 1's loads
    // into registers immediately after so their latency overlaps half-0 MFMAs.
    ull r2[16];
#pragma unroll 4
    for (int q = 0; q < 16; ++q) {
        int g = q * 256 + tid;
        lds_h[g] = AGLD(src + g);
    }
#pragma unroll
    for (int q = 0; q < 16; ++q)
        r2[q] = AGLD(src + 4096 + q * 256 + tid);
    __syncthreads();

    {   // 32 MFMAs over K-half 0 (A from L2, B from LDS).
        const half8v* __restrict__ lb = ((const half8v*)lds_h) + l;
        const half8v* __restrict__ ap = apb;
#pragma unroll 8
        for (int c = 0; c < 32; ++c) {
            half8v av = ap[c * 64];      // global 16-B coalesced (L2 hit)
            half8v bv = lb[c * 64];      // ds_read_b128, conflict-free
            if (c & 1) acc1 = __builtin_amdgcn_mfma_f32_16x16x32_f16(av, bv, acc1, 0, 0, 0);
            else       acc0 = __builtin_amdgcn_mfma_f32_16x16x32_f16(av, bv, acc0, 0, 0, 0);
        }
    }
    __syncthreads();                     // all ds_reads of half 0 done

    // Write prefetched half 1 (K-chunks 32..63) into LDS.
#pragma unroll
    for (int q = 0; q < 16; ++q) lds_h[q * 256 + tid] = r2[q];
    __syncthreads();

    {   // 32 MFMAs over K-half 1.
        const half8v* __restrict__ lb = ((const half8v*)lds_h) + l;
        const half8v* __restrict__ ap = apb + 32 * 64;
#pragma unroll 8
        for (int c = 0; c < 32; ++c) {
            half8v av = ap[c * 64];
            half8v bv = lb[c * 64];
            if (c & 1) acc1 = __builtin_amdgcn_mfma_f32_16x16x32_f16(av, bv, acc1, 0, 0, 0);
            else       acc0 = __builtin_amdgcn_mfma_f32_16x16x32_f16(av, bv, acc0, 0, 0, 0);
        }
    }
    // No trailing sync: next LDS write happens after the barrier's entry
    // __syncthreads (or never, on the last step).
    float4v hs = acc0 + acc1;

    // Epilogue: h = A*h + bu_t (C-layout: col j = lane&15, row = quad*4+r).
    const int t = j * CLEN - WARM + k;
    float4v bv4;
    if (t >= 0) {
        bv4 = *(const float4v*)(bu + (size_t)t * ORDER + mrow);  // plain, L2
    } else {
        float v = (t == -1) ? 1.0f : 0.0f;   // bu_{-1}=1 injects h0=1 exactly
        bv4 = {v, v, v, v};
    }
    float4v h = hs + bv4;

    // Next state: atomic EXCHANGE (RMW at the MALL -> cross-XCD coherent).
    union { half4v hh; ull u; } cv;
    cv.hh[0] = (_Float16)h[0]; cv.hh[1] = (_Float16)h[1];
    cv.hh[2] = (_Float16)h[2]; cv.hh[3] = (_Float16)h[3];
    (void)__hip_atomic_exchange(dst + granH, cv.u, __ATOMIC_RELAXED,
                                __HIP_MEMORY_SCOPE_AGENT);

    // Record tanh output into registers (static slot SEG; flushed per octave).
    if (SEG >= 0) {
#pragma unroll
        for (int r = 0; r < 4; ++r) {
            float x = h[r];
            float e = __expf(-2.0f * fabsf(x));
            float o = copysignf((1.0f - e) / (1.0f + e), x);
            unsigned hu = (unsigned)__half_as_ushort(__float2half_rn(o));
            if (SEG & 1) oreg[r][SEG >> 1] = (oreg[r][SEG >> 1] & 0xFFFFu) | (hu << 16);
            else         oreg[r][SEG >> 1] = hu;
        }
    }

    if (!last) domain_barrier(slots, rg, (unsigned)(k + 1));
}

// Persistent step kernel (r2 structure; only WARM differs). Tiling: 128
// row-blocks (16 rows) x 8 j-groups (16 chunks); wg = 4 waves = 4
// consecutive row-blocks sharing an LDS-staged j-panel (2 x 32 KB halves).
// H: 8-B agent-scope atomic exchange stores / agent-scope staged loads.
// Outputs: fp16 pairs in registers, flushed every 8 steps as 32-B sectors.
__global__ __launch_bounds__(256) void step_kernel(const _Float16* __restrict__ Ap,
                                                   const float* __restrict__ bu,
                                                   _Float16* __restrict__ Ha,
                                                   _Float16* __restrict__ Hb,
                                                   float* __restrict__ out,
                                                   ull* __restrict__ bar) {
    const int w    = blockIdx.x;         // 0..255
    const int xcd  = w & 7;              // MI355X blockIdx%8 -> XCD (perf only)
    const int idx  = w >> 3;             // 0..31
    const int rg   = xcd * 4 + (idx & 3);// 64-row group: 256-row slab per XCD
    const int jg   = idx >> 2;           // 0..7: 16-chunk j-panel
    const int tid  = threadIdx.x;
    const int wave = tid >> 6;           // 0..3 -> row-block within group
    const int l    = tid & 63;
    const int n    = l & 15;
    const int quad = l >> 4;
    const int R    = rg * 4 + wave;      // global 16-row block, 0..127
    const int i0   = R * 16;
    const int j    = jg * 16 + n;        // this lane's chunk id
    const int mrow = i0 + quad * 4;

    __shared__ ull lds_h[4096];          // 32 KB (exact r2-proven LDS profile)

    // Barrier state for domain jg: 32 slots x 32 B.
    ull* slots = bar + (size_t)jg * 128;

    // A fragments for this wave (coalesced 16-B loads, L2-resident).
    const half8v* __restrict__ apb = ((const half8v*)Ap) + (size_t)R * 4096 + l;

    // H-store granule within panel jg (B-fragment order, r6-verified).
    const int granH = (((mrow >> 5) * 64) + (((mrow >> 3) & 3) * 16) + n) * 2
                    + ((mrow >> 2) & 1);

    unsigned oreg[4][4];                 // 4 rows x 8 t-segments (fp16 pairs)

    // Phase A: warmup steps k = 0..WARM-2 (no output emitted).
    for (int k = 0; k < WARM - 1; ++k)
        do_step<-1>(k, false, apb, bu, Ha, Hb, slots, lds_h,
                    tid, l, rg, jg, j, mrow, granH, oreg);

    // Phase B: 4 octaves x 8 steps, k = WARM-1 .. S_STEPS-1; flush per octave.
    for (int g = 0; g < 4; ++g) {
        const int k0 = WARM - 1 + g * 8;
        const bool lg = (g == 3);
        do_step<0>(k0 + 0, false, apb, bu, Ha, Hb, slots, lds_h, tid, l, rg, jg, j, mrow, granH, oreg);
        do_step<1>(k0 + 1, false, apb, bu, Ha, Hb, slots, lds_h, tid, l, rg, jg, j, mrow, granH, oreg);
        do_step<2>(k0 + 2, false, apb, bu, Ha, Hb, slots, lds_h, tid, l, rg, jg, j, mrow, granH, oreg);
        do_step<3>(k0 + 3, false, apb, bu, Ha, Hb, slots, lds_h, tid, l, rg, jg, j, mrow, granH, oreg);
        do_step<4>(k0 + 4, false, apb, bu, Ha, Hb, slots, lds_h, tid, l, rg, jg, j, mrow, granH, oreg);
        do_step<5>(k0 + 5, false, apb, bu, Ha, Hb, slots, lds_h, tid, l, rg, jg, j, mrow, granH, oreg);
        do_step<6>(k0 + 6, false, apb, bu, Ha, Hb, slots, lds_h, tid, l, rg, jg, j, mrow, granH, oreg);
        do_step<7>(k0 + 7, lg,    apb, bu, Ha, Hb, slots, lds_h, tid, l, rg, jg, j, mrow, granH, oreg);

        // Flush octave g: rows mrow..mrow+3, t = j*32 + g*8 .. +8 (32-B sectors,
        // consecutive n-lanes -> consecutive 128-B lines of the same row).
        float* __restrict__ ob = out + (size_t)mrow * T_LEN + j * 32 + g * 8;
#pragma unroll
        for (int r = 0; r < 4; ++r) {
            float4v f0, f1;
#pragma unroll
            for (int p = 0; p < 2; ++p) {
                unsigned v0 = oreg[r][p * 2 + 0];
                unsigned v1 = oreg[r][p * 2 + 1];
                float a0 = __half2float(__ushort_as_half((ushort)(v0 & 0xFFFFu)));
                float a1 = __half2float(__ushort_as_half((ushort)(v0 >> 16)));
                float a2 = __half2float(__ushort_as_half((ushort)(v1 & 0xFFFFu)));
                float a3 = __half2float(__ushort_as_half((ushort)(v1 >> 16)));
                if (p == 0) f0 = {a0, a1, a2, a3};
                else        f1 = {a0, a1, a2, a3};
            }
            *(float4v*)(ob + (size_t)r * T_LEN)     = f0;
            *(float4v*)(ob + (size_t)r * T_LEN + 4) = f1;
        }
    }
}

extern "C" void kernel_launch(void* const* d_in, const int* in_sizes, int n_in,
                              void* d_out, int out_size, void* d_ws, size_t ws_size,
                              hipStream_t stream) {
    const float* u  = (const float*)d_in[0];   // [IN_DIM][T_LEN]
    const float* A  = (const float*)d_in[1];   // [ORDER][ORDER]
    const float* Bw = (const float*)d_in[2];   // [ORDER][IN_DIM]
    float* out = (float*)d_out;                // [ORDER][T_LEN]

    char* ws = (char*)d_ws;
    float*     bu  = (float*)ws;                                 // 33,554,432 B
    _Float16*  Ap  = (_Float16*)(ws + 33554432);                 //  8,388,608 B
    _Float16*  Ha  = (_Float16*)(ws + 41943040);                 //    524,288 B
    _Float16*  Hb  = (_Float16*)(ws + 42467328);                 //    524,288 B
    ull*       bar = (ull*)(ws + 42991616);                      //      8,192 B

    // H_0 = zeros in Ha; barrier slots = 0 (ws poisoned 0xAA per call).
    zero_kernel<<<dim3(512), 256, 0, stream>>>((float*)Ha, NCHUNK * ORDER / 2);
    zero_kernel<<<dim3(8), 256, 0, stream>>>((float*)bar, 2048);
    bu_kernel<<<dim3(64, 8), 256, 0, stream>>>(u, Bw, bu);
    pack_kernel<<<dim3(2048), 256, 0, stream>>>(A, Ap);

    void* args[] = {(void*)&Ap, (void*)&bu, (void*)&Ha, (void*)&Hb,
                    (void*)&out, (void*)&bar};
    hipError_t ce = hipLaunchCooperativeKernel((void*)step_kernel, dim3(NWG),
                                               dim3(256), args, 0, stream);
    if (ce != hipSuccess) {
        // Silent-rejection insurance: at 32 KB LDS / ~100 VGPR, >=4 wg/CU
        // fit, so all 256 wgs co-reside on 256 CUs under a plain launch and
        // the slot barrier remains deadlock-free.
        (void)hipGetLastError();
        step_kernel<<<dim3(NWG), dim3(256), 0, stream>>>(Ap, bu, Ha, Hb, out,
                                                         (ull*)bar);
    }
}